// Round 4
// baseline (414.857 us; speedup 1.0000x reference)
//
#include <hip/hip_runtime.h>
#include <cstdint>

// Problem constants
#define NB 32
#define IC 256
#define OC 256
#define H 56
#define WIDTH 56
#define OH 54
#define OW 54
#define HW (H*WIDTH)          // 3136
#define OHW (OH*OW)           // 2916

// Tiling: m-tile = 6 oh x 16 ow (96 m), o-tile 128 (ob in {0,1})
// oh tiles: 9 (54/6). ow tiles: starts {0,16,32,38} (overlap 38..47, identical writes)
// K order: cb(8 c-blocks of 32) x tap(9) x c(32)
#define CBLK 8
#define PXC 40                 // padded shorts per pixel in LDS patch (80 B: bank-balanced)
#define PIH 8                  // patch rows  = 6 + 2
#define PIW 18                 // patch cols  = 16 + 2

// Static device scratch:
// W pre-tiled: [ob(2)][cb(8)][tap(9)][o'(128)][c'(32)] bf16 bits (1.18 MB, L2-resident)
__device__ __align__(16) unsigned short g_qwt[2*CBLK*9*128*32];
// x as NHWC bf16: [n][ih][iw][c]
__device__ __align__(16) unsigned short g_xq[NB*HW*IC];

typedef __bf16 bf16x8 __attribute__((ext_vector_type(8)));
typedef float  f32x4  __attribute__((ext_vector_type(4)));

__device__ inline unsigned short f32_bf16(float f) {
  union { float f; unsigned int u; } v; v.f = f;
  unsigned int u = v.u;
  return (unsigned short)((u + 0x7FFFu + ((u >> 16) & 1u)) >> 16);  // RNE
}

// ---- Kernel 1: binarize + pre-tile weights -------------------------------
// dst L over [ob][cb][tap][o'(128)][c'(32)]
__global__ __launch_bounds__(256) void repack_w(const float* __restrict__ w) {
  int L = blockIdx.x * 256 + threadIdx.x;           // < 589824
  int img = L >> 12;                                // [ob][cb][tap], 144 images of 4096
  int o_  = (L >> 5) & 127;
  int c_  = L & 31;
  int tap = img % 9;
  int t2  = img / 9;
  int cb  = t2 & 7;
  int ob  = t2 >> 3;
  int o = ob*128 + o_;
  int c = cb*32 + c_;
  float v = w[o*2304 + c*9 + tap];
  unsigned short s = (v > 0.f) ? 0x3F80u : ((v < 0.f) ? 0xBF80u : 0u);  // sign() in bf16
  g_qwt[L] = s;
}

// ---- Kernel 2: x NCHW fp32 -> NHWC bf16, fully vectorized ----------------
__global__ __launch_bounds__(256) void xform_x(const float* __restrict__ x) {
  __shared__ unsigned short tile[64][IC + 8];       // row stride 528 B (16B-aligned)
  const int t   = threadIdx.x;
  const int n   = blockIdx.y;
  const int hw0 = blockIdx.x * 64;
  const int cl  = t >> 4;                           // 0..15
  const int hl  = (t & 15) * 4;                     // 0..60
  #pragma unroll 4
  for (int j = 0; j < 16; ++j) {
    int c = j*16 + cl;
    const float4 v = *(const float4*)(&x[(n*IC + c)*HW + hw0 + hl]);
    tile[hl+0][c] = f32_bf16(v.x);
    tile[hl+1][c] = f32_bf16(v.y);
    tile[hl+2][c] = f32_bf16(v.z);
    tile[hl+3][c] = f32_bf16(v.w);
  }
  __syncthreads();
  const int ch = (t & 31) * 8;                      // c chunk (8 bf16 = 16 B)
  const int hr = t >> 5;                            // 0..7
  #pragma unroll
  for (int p = 0; p < 8; ++p) {
    int hwi = p*8 + hr;
    *(uint4*)(&g_xq[(n*HW + hw0 + hwi)*IC + ch]) = *(const uint4*)(&tile[hwi][ch]);
  }
}

// ---- Kernel 3: implicit-GEMM binary conv, tap-reuse structure ------------
// Per c-block (8 supersteps): stage halo'd X patch ONCE (8x18 px x 32c,
// 80 B/px padded), then 9 taps read shifted windows via ds_read_b128 with
// compile-time immediate offsets. W direct global->VGPR (L2-resident,
// no barrier between taps -> real overlap with MFMA). 16 barriers total.
__global__ __launch_bounds__(256) void bconv_gemm(float* __restrict__ out) {
  __shared__ __align__(16) unsigned short Xs[PIH*PIW*PXC];   // 11520 B
  const int t  = threadIdx.x;
  const int bx = blockIdx.x;              // (n, oh_i, ow_i)
  const int ob = blockIdx.y;

  const int ow_i = bx & 3;
  const int t2   = bx >> 2;
  const int oh_i = t2 % 9;
  const int n    = t2 / 9;
  const int oh0  = oh_i * 6;
  const int ow0  = (ow_i == 3) ? 38 : ow_i * 16;

  // Staging descriptors: 576 16B-chunks (8x18 px x 4 chunks); thread t owns
  // chunks t, t+256, and (t<64) t+512. Wave 0 only takes the 3rd -> wave-uniform.
  int src0, src1, src2 = 0, dst0, dst1, dst2 = 0;
  {
    int e, p, q, ih_l, iw_l;
    e = t;        p = e >> 2; q = e & 3; ih_l = p / PIW; iw_l = p - ih_l*PIW;
    src0 = ((n*H + oh0 + ih_l)*WIDTH + ow0 + iw_l)*IC + q*8;
    dst0 = p*PXC + q*8;
    e = t + 256;  p = e >> 2; q = e & 3; ih_l = p / PIW; iw_l = p - ih_l*PIW;
    src1 = ((n*H + oh0 + ih_l)*WIDTH + ow0 + iw_l)*IC + q*8;
    dst1 = p*PXC + q*8;
    if (t < 64) {
      e = t + 512; p = e >> 2; q = e & 3; ih_l = p / PIW; iw_l = p - ih_l*PIW;
      src2 = ((n*H + oh0 + ih_l)*WIDTH + ow0 + iw_l)*IC + q*8;
      dst2 = p*PXC + q*8;
    }
  }

  const int lane = t & 63;
  const int wv   = t >> 6;
  const int col  = lane & 15;
  const int quad = lane >> 4;
  const int wo   = (wv & 1) * 64;        // wave's o-offset (of 128)
  const int mh   = wv >> 1;              // wave's oh-half: rows 3*mh..3*mh+2

  // A-frag global offsets within a (cb,tap) W image [o'(128)][c'(32)]
  int aoff[4];
  #pragma unroll
  for (int i = 0; i < 4; ++i) aoff[i] = (wo + i*16 + col)*32 + quad*8;
  // B-frag LDS bases (shorts); tap adds (kh*PIW+kw)*PXC as compile-time imm
  int boff[3];
  #pragma unroll
  for (int i = 0; i < 3; ++i) boff[i] = ((3*mh + i)*PIW + col)*PXC + quad*8;

  const unsigned short* wbase = g_qwt + ob*(CBLK*9*4096);

  f32x4 acc[4][3];
  #pragma unroll
  for (int io = 0; io < 4; ++io)
    #pragma unroll
    for (int im = 0; im < 3; ++im)
      acc[io][im] = (f32x4){0.f, 0.f, 0.f, 0.f};

  for (int cb = 0; cb < CBLK; ++cb) {
    const int csh = cb * 32;             // c offset in shorts
    __syncthreads();                     // patch free (prev taps done)
    {
      uint4 v0 = *(const uint4*)(&g_xq[src0 + csh]);
      uint4 v1 = *(const uint4*)(&g_xq[src1 + csh]);
      uint4 v2;
      if (t < 64) v2 = *(const uint4*)(&g_xq[src2 + csh]);
      *(uint4*)(&Xs[dst0]) = v0;
      *(uint4*)(&Xs[dst1]) = v1;
      if (t < 64) *(uint4*)(&Xs[dst2]) = v2;
    }
    __syncthreads();                     // patch visible

    const unsigned short* wimg = wbase + cb*(9*4096);
    #pragma unroll
    for (int tap = 0; tap < 9; ++tap) {
      const int kh = tap / 3, kw = tap % 3;
      bf16x8 av[4], bv[3];
      #pragma unroll
      for (int i = 0; i < 4; ++i)
        av[i] = *(const bf16x8*)(wimg + tap*4096 + aoff[i]);
      #pragma unroll
      for (int i = 0; i < 3; ++i)
        bv[i] = *(const bf16x8*)(&Xs[boff[i] + (kh*PIW + kw)*PXC]);  // imm offset
      #pragma unroll
      for (int io = 0; io < 4; ++io)
        #pragma unroll
        for (int im = 0; im < 3; ++im)
          acc[io][im] = __builtin_amdgcn_mfma_f32_16x16x32_bf16(av[io], bv[im], acc[io][im], 0, 0, 0);
    }
  }

  // Epilogue: D row=(quad*4+r) -> o, col -> ow. All stores in-bounds;
  // overlapped ow-tiles write identical values.
  #pragma unroll
  for (int im = 0; im < 3; ++im) {
    const int oh = oh0 + 3*mh + im;
    const int ow = ow0 + col;
    #pragma unroll
    for (int io = 0; io < 4; ++io) {
      const int o = ob*128 + wo + io*16 + quad*4;
      float* p = out + ((n*OC + o)*OH + oh)*OW + ow;
      #pragma unroll
      for (int r = 0; r < 4; ++r)
        p[r*OHW] = acc[io][im][r];
    }
  }
}

extern "C" void kernel_launch(void* const* d_in, const int* in_sizes, int n_in,
                              void* d_out, int out_size, void* d_ws, size_t ws_size,
                              hipStream_t stream) {
  const float* x = (const float*)d_in[0];   // [32,256,56,56] fp32
  const float* w = (const float*)d_in[1];   // [256,256,3,3] fp32
  float* out = (float*)d_out;               // [32,256,54,54] fp32

  repack_w<<<dim3(589824/256), 256, 0, stream>>>(w);
  xform_x <<<dim3(HW/64, NB), 256, 0, stream>>>(x);
  bconv_gemm<<<dim3(NB*9*4, 2), 256, 0, stream>>>(out);
}